// Round 1
// baseline (2646.039 us; speedup 1.0000x reference)
//
#include <hip/hip_runtime.h>
#include <stdint.h>

#define NB 4
#define NC 512
#define NH 64
#define NW 96
#define NA 9
#define NPIX (NB*NA*NH*NW)   // 221184
#define KSEL 2048
#define NOUT 50
#define THRS 0.05f

#define HIST_BASE 0x3D4CCu   // bits(0.05f)>>12
#define HIST_SIZE 9024       // covers through bits(1.0f)>>12 = 0x3F800
#define CAND_CAP 8192

__device__ const float ANC_W[9] = {128.f,128.f,256.f,256.f,256.f,512.f,512.f,512.f,1024.f};
__device__ const float ANC_H[9] = {128.f,256.f,128.f,256.f,512.f,256.f,512.f,1024.f,512.f};

// ---------------- weight transpose: w1[co][ci][ky][kx] -> wT[(ky*3+kx)][ci][co]
__global__ void transpose_w1(const float* __restrict__ w1, float* __restrict__ wT) {
    const int i = blockIdx.x * 256 + threadIdx.x;
    if (i < 9 * 512 * 512) {
        const int kk  = i / (512 * 512);
        const int rem = i % (512 * 512);
        const int ci  = rem >> 9;
        const int co  = rem & 511;
        wT[i] = w1[((size_t)co * 512 + ci) * 9 + kk];
    }
}

// ---------------- fused conv3x3 + bias + 1x1 heads + softmax ----------------
// block: 256 threads, tile 16x4 pixels, all 512 output channels in registers.
// thread t: cg = t&31 -> co = q*128 + cg*4 + c (q=0..3,c=0..3); pg = t>>5 ->
// pixels row py=pg>>1, cols px0=(pg&1)*8 .. +7.
__global__ __launch_bounds__(256, 2) void conv_fused(
    const float* __restrict__ x, const float* __restrict__ wT,
    const float* __restrict__ b1, const float* __restrict__ wcls,
    const float* __restrict__ bcls, const float* __restrict__ wreg,
    const float* __restrict__ breg,
    float* __restrict__ scores, float* __restrict__ regs)
{
    __shared__ __align__(16) float smem[15576];   // 62304 B
    const int t  = threadIdx.x;
    const int x0 = blockIdx.x * 16;
    const int y0 = blockIdx.y * 4;
    const int b  = blockIdx.z;
    const int cg = t & 31;
    const int pg = t >> 5;

    float acc[8][16];
#pragma unroll
    for (int j = 0; j < 8; ++j)
#pragma unroll
        for (int c = 0; c < 16; ++c) acc[j][c] = 0.f;

    float* xs  = smem;        // [8 ci][6 rows][20 cols]
    float* wts = smem + 960;  // [3 kx][8 ci][512 co]

    const float* xb = x + (size_t)b * NC * NH * NW;

    for (int cc = 0; cc < 64; ++cc) {
        const int ci0 = cc * 8;
        __syncthreads();
        // stage x tile (with 1-px halo, zero padded)
        for (int e = t; e < 960; e += 256) {
            const int ci = e / 120;
            const int rr = (e % 120) / 20;
            const int c0 = e % 20;
            const int gy = y0 + rr - 1;
            const int gx = x0 + c0 - 1;
            float v = 0.f;
            if (c0 < 18 && gy >= 0 && gy < NH && gx >= 0 && gx < NW)
                v = xb[(ci0 + ci) * (NH * NW) + gy * NW + gx];
            xs[e] = v;
        }
        for (int ky = 0; ky < 3; ++ky) {
            __syncthreads();
            const float4* wsrc = (const float4*)wT;
#pragma unroll
            for (int k = 0; k < 12; ++k) {
                const int idx4 = t + k * 256;        // < 3072
                const int kx   = idx4 >> 10;
                const int rem  = idx4 & 1023;
                const int ci   = rem >> 7;
                const int co4  = rem & 127;
                ((float4*)wts)[idx4] =
                    wsrc[((size_t)(ky * 3 + kx) * NC + (ci0 + ci)) * 128 + co4];
            }
            __syncthreads();
            const int rowbase = ((pg >> 1) + ky) * 20 + ((pg & 1) * 8);
            for (int ci = 0; ci < 8; ++ci) {
                float ar[10];
                const float* xrow = &xs[ci * 120 + rowbase];
#pragma unroll
                for (int u = 0; u < 10; ++u) ar[u] = xrow[u];
#pragma unroll
                for (int kx = 0; kx < 3; ++kx) {
                    const float4* wr = (const float4*)&wts[(kx * 8 + ci) * 512];
                    const float4 w0 = wr[cg];
                    const float4 w1v = wr[cg + 32];
                    const float4 w2 = wr[cg + 64];
                    const float4 w3 = wr[cg + 96];
                    const float bv[16] = {w0.x,w0.y,w0.z,w0.w, w1v.x,w1v.y,w1v.z,w1v.w,
                                          w2.x,w2.y,w2.z,w2.w, w3.x,w3.y,w3.z,w3.w};
#pragma unroll
                    for (int j = 0; j < 8; ++j) {
                        const float a = ar[j + kx];
#pragma unroll
                        for (int c = 0; c < 16; ++c) acc[j][c] += a * bv[c];
                    }
                }
            }
        }
    }

    // add conv bias b1
    float bias1[16];
#pragma unroll
    for (int q = 0; q < 4; ++q)
#pragma unroll
        for (int c = 0; c < 4; ++c) bias1[q * 4 + c] = b1[q * 128 + cg * 4 + c];
#pragma unroll
    for (int j = 0; j < 8; ++j)
#pragma unroll
        for (int i2 = 0; i2 < 16; ++i2) acc[j][i2] += bias1[i2];

    // ---- phase 2: 1x1 heads (cls 18 + reg 36 = 54 outputs per pixel) ----
    float* fbuf = smem;          // [128 co_local][66]
    float* wcr  = smem + 8448;   // [54 oc][132]
    const int pxg = t >> 4;      // 0..15 (4 px each)
    const int g16 = t & 15;
    float acc1[4][4];
#pragma unroll
    for (int p = 0; p < 4; ++p)
#pragma unroll
        for (int j2 = 0; j2 < 4; ++j2) acc1[p][j2] = 0.f;

#pragma unroll
    for (int ch = 0; ch < 4; ++ch) {
        __syncthreads();
#pragma unroll
        for (int j = 0; j < 8; ++j)
#pragma unroll
            for (int c = 0; c < 4; ++c)
                fbuf[(cg * 4 + c) * 66 + (pg * 8 + j)] = acc[j][ch * 4 + c];
        for (int e = t; e < 6912; e += 256) {
            const int oc = e / 128;
            const int co = e % 128;
            wcr[oc * 132 + co] = (oc < 18) ? wcls[oc * 512 + ch * 128 + co]
                                           : wreg[(oc - 18) * 512 + ch * 128 + co];
        }
        __syncthreads();
        for (int co = 0; co < 128; ++co) {
            float wv[4];
#pragma unroll
            for (int j2 = 0; j2 < 4; ++j2) {
                const int oc = g16 + 16 * j2;
                wv[j2] = (oc < 54) ? wcr[oc * 132 + co] : 0.f;
            }
#pragma unroll
            for (int p = 0; p < 4; ++p) {
                const float v = fbuf[co * 66 + pxg * 4 + p];
#pragma unroll
                for (int j2 = 0; j2 < 4; ++j2) acc1[p][j2] += v * wv[j2];
            }
        }
    }

    __syncthreads();
    float* clsreg = smem;        // [64 px][56]
#pragma unroll
    for (int p = 0; p < 4; ++p)
#pragma unroll
        for (int j2 = 0; j2 < 4; ++j2) {
            const int oc = g16 + 16 * j2;
            if (oc < 54) clsreg[(pxg * 4 + p) * 56 + oc] = acc1[p][j2];
        }
    __syncthreads();

    if (t < 64) {
        const int gy = y0 + (t >> 4);
        const int gx = x0 + (t & 15);
        float lg[18];
        float m = -1e30f;
#pragma unroll
        for (int oc = 0; oc < 18; ++oc) {
            lg[oc] = clsreg[t * 56 + oc] + bcls[oc];
            m = fmaxf(m, lg[oc]);
        }
        float sum = 0.f;
#pragma unroll
        for (int oc = 0; oc < 18; ++oc) { lg[oc] = expf(lg[oc] - m); sum += lg[oc]; }
        const float inv = 1.f / sum;
#pragma unroll
        for (int a = 0; a < 9; ++a) {
            const int idx = ((b * NA + a) * NH + gy) * NW + gx;
            scores[idx] = lg[2 * a + 1] * inv;
#pragma unroll
            for (int c2 = 0; c2 < 4; ++c2)
                regs[(size_t)idx * 4 + c2] = clsreg[t * 56 + 18 + a * 4 + c2] + breg[a * 4 + c2];
        }
    }
}

// ---------------- histogram over score float bits ----------------
__global__ void hist_k(const float* __restrict__ scores, uint32_t* __restrict__ hist) {
    const int i = blockIdx.x * 256 + threadIdx.x;
    const float s = scores[i];
    if (s >= THRS) {
        int bkt = (int)(__float_as_uint(s) >> 12) - (int)HIST_BASE;
        bkt = min(max(bkt, 0), HIST_SIZE - 1);
        atomicAdd(&hist[bkt], 1u);
    }
}

// ---------------- suffix scan -> cutoff bucket ----------------
__global__ void scan_k(const uint32_t* __restrict__ hist, uint32_t* __restrict__ ctl) {
    __shared__ uint32_t ssum[1024];
    const int t = threadIdx.x;
    uint32_t s = 0;
#pragma unroll
    for (int u = 0; u < 9; ++u) {
        const int bkt = t * 9 + u;
        if (bkt < HIST_SIZE) s += hist[bkt];
    }
    const uint32_t mysum = s;
    ssum[t] = s;
    __syncthreads();
    for (int off = 1; off < 1024; off <<= 1) {
        uint32_t v = (t + off < 1024) ? ssum[t + off] : 0u;
        __syncthreads();
        ssum[t] += v;
        __syncthreads();
    }
    const uint32_t total = ssum[0];
    const uint32_t above = (t < 1023) ? ssum[t + 1] : 0u;
    if (total < KSEL) {
        if (t == 0) ctl[0] = HIST_BASE;           // collect everything
    } else if (above < KSEL && above + mysum >= KSEL) {
        uint32_t run = above;
        for (int u = 8; u >= 0; --u) {
            const int bkt = t * 9 + u;
            if (bkt >= HIST_SIZE) continue;
            run += hist[bkt];
            if (run >= KSEL) { ctl[0] = HIST_BASE + (uint32_t)bkt; break; }
        }
    }
}

// ---------------- compact candidates above cutoff ----------------
__global__ void collect_k(const float* __restrict__ scores, uint32_t* __restrict__ ctl,
                          uint64_t* __restrict__ cand) {
    const int i = blockIdx.x * 256 + threadIdx.x;
    const float s = scores[i];
    if (s >= THRS) {
        const uint32_t bits = __float_as_uint(s);
        if ((bits >> 12) >= ctl[0]) {
            const uint32_t pos = atomicAdd(&ctl[1], 1u);
            if (pos < CAND_CAP)
                cand[pos] = ((uint64_t)bits << 32) | (uint64_t)(0xFFFFFFFFu - (uint32_t)i);
        }
    }
}

// ---------------- single-block bitonic sort (desc) + box decode ----------------
__global__ void sort_decode_k(const uint64_t* __restrict__ cand, const uint32_t* __restrict__ ctl,
                              const float* __restrict__ regs,
                              const int* __restrict__ hp, const int* __restrict__ wp,
                              float* __restrict__ tops_s, float* __restrict__ boxes) {
    __shared__ uint64_t keys[CAND_CAP];
    const int t = threadIdx.x;
    const int M = min((int)ctl[1], CAND_CAP);
    const int N = (M <= 4096) ? 4096 : 8192;
    for (int k = t; k < N; k += 1024) keys[k] = (k < M) ? cand[k] : 0ull;
    __syncthreads();
    for (int size = 2; size <= N; size <<= 1) {
        for (int stride = size >> 1; stride > 0; stride >>= 1) {
            for (int k = t; k < N; k += 1024) {
                const int p = k ^ stride;
                if (p > k) {
                    const uint64_t a = keys[k], bb = keys[p];
                    const bool sw = ((k & size) == 0) ? (a < bb) : (a > bb);
                    if (sw) { keys[k] = bb; keys[p] = a; }
                }
            }
            __syncthreads();
        }
    }
    const int w_in = wp[0], h_in = hp[0];
    const float offx = (float)((w_in - 16) % 16) * 0.5f + 8.0f;
    const float offy = (float)((h_in - 16) % 16) * 0.5f + 8.0f;
    for (int k = t; k < KSEL; k += 1024) {
        const uint64_t key = keys[k];
        float sc = -1.f, x1 = 0.f, y1 = 0.f, x2 = 0.f, y2 = 0.f;
        if (k < M && key != 0ull) {
            const uint32_t idx = 0xFFFFFFFFu - (uint32_t)(key & 0xFFFFFFFFull);
            sc = __uint_as_float((uint32_t)(key >> 32));
            const int a  = (int)(idx / (NH * NW)) % NA;
            const int yy = (int)(idx / NW) % NH;
            const int xx = (int)(idx % NW);
            const float4 r = ((const float4*)regs)[idx];
            const float aw = ANC_W[a], ah = ANC_H[a];
            const float cx = (float)xx * 16.f + offx;
            const float cy = (float)yy * 16.f + offy;
            const float bx = r.x * aw + cx;
            const float by = r.y * ah + cy;
            const float bw = expf(r.z) * aw;
            const float bh = expf(r.w) * ah;
            x1 = bx - bw * 0.5f; y1 = by - bh * 0.5f;
            x2 = bx + bw * 0.5f; y2 = by + bh * 0.5f;
        }
        tops_s[k] = sc;
        ((float4*)boxes)[k] = make_float4(x1, y1, x2, y2);
    }
}

// ---------------- pairwise IoU suppression bitmask ----------------
__global__ void iou_k(const float* __restrict__ boxes, uint64_t* __restrict__ mask) {
    __shared__ float4 jb[64];
    const int t = threadIdx.x;
    const int bi = blockIdx.x, bj = blockIdx.y;
    jb[t] = ((const float4*)boxes)[bj * 64 + t];
    __syncthreads();
    const int i = bi * 64 + t;
    const float4 mb = ((const float4*)boxes)[i];
    const float areai = (mb.z - mb.x) * (mb.w - mb.y);
    uint64_t w = 0;
    for (int jj = 0; jj < 64; ++jj) {
        const float4 ob = jb[jj];
        const int j = bj * 64 + jj;
        const float ix1 = fmaxf(mb.x, ob.x);
        const float iy1 = fmaxf(mb.y, ob.y);
        const float ix2 = fminf(mb.z, ob.z);
        const float iy2 = fminf(mb.w, ob.w);
        const float inter = fmaxf(ix2 - ix1, 0.f) * fmaxf(iy2 - iy1, 0.f);
        const float areaj = (ob.z - ob.x) * (ob.w - ob.y);
        const float iou = inter / (areai + areaj - inter + 1e-9f);
        if (iou > 0.7f && j > i) w |= (1ull << jj);
    }
    mask[(size_t)i * 32 + bj] = w;
}

// ---------------- sequential greedy NMS scan + output ----------------
__global__ void nms_k(const float* __restrict__ tops_s, const float* __restrict__ boxes,
                      const uint64_t* __restrict__ mask, float* __restrict__ out) {
    __shared__ uint64_t remv[32];
    __shared__ float ssc[KSEL];
    __shared__ int sel[NOUT];
    const int t = threadIdx.x;      // 64 threads = 1 wave
    for (int k = t; k < KSEL; k += 64) ssc[k] = tops_s[k];
    if (t < 32) remv[t] = 0ull;
    __syncthreads();
    int cnt = 0;                    // wave-uniform
    for (int i = 0; i < KSEL; ++i) {
        const uint64_t rw = remv[i >> 6];
        const bool sup = (rw >> (i & 63)) & 1ull;
        const bool val = (ssc[i] >= THRS);
        if (val && !sup) {
            if (t < 32) remv[t] |= mask[(size_t)i * 32 + t];
            if (cnt < NOUT && t == 0) sel[cnt] = i;
            ++cnt;
        }
        __syncthreads();
    }
    for (int k = t; k < NOUT; k += 64) {
        float s = 0.f;
        float4 bb = make_float4(0.f, 0.f, 0.f, 0.f);
        if (k < cnt) { const int i = sel[k]; s = ssc[i]; bb = ((const float4*)boxes)[i]; }
        out[k] = s;
        out[NOUT + k * 4 + 0] = bb.x;
        out[NOUT + k * 4 + 1] = bb.y;
        out[NOUT + k * 4 + 2] = bb.z;
        out[NOUT + k * 4 + 3] = bb.w;
    }
}

extern "C" void kernel_launch(void* const* d_in, const int* in_sizes, int n_in,
                              void* d_out, int out_size, void* d_ws, size_t ws_size,
                              hipStream_t stream) {
    const float* x    = (const float*)d_in[0];
    const float* w1   = (const float*)d_in[1];
    const float* b1   = (const float*)d_in[2];
    const float* wcls = (const float*)d_in[3];
    const float* bcls = (const float*)d_in[4];
    const float* wreg = (const float*)d_in[5];
    const float* breg = (const float*)d_in[6];
    const int*   hp   = (const int*)d_in[7];
    const int*   wp   = (const int*)d_in[8];
    float* out = (float*)d_out;

    char* ws = (char*)d_ws;
    size_t off = 0;
    auto carve = [&](size_t bytes) -> void* {
        void* p = ws + off;
        off = (off + bytes + 255) & ~(size_t)255;
        return p;
    };
    float*    wT     = (float*)carve((size_t)9 * 512 * 512 * 4);   // 9.44 MB
    float*    scores = (float*)carve((size_t)NPIX * 4);            // 0.88 MB
    float*    regs   = (float*)carve((size_t)NPIX * 16);           // 3.54 MB
    uint32_t* hist   = (uint32_t*)carve((size_t)HIST_SIZE * 4);
    uint32_t* ctl    = (uint32_t*)carve(256);
    uint64_t* cand   = (uint64_t*)carve((size_t)CAND_CAP * 8);
    float*    tops_s = (float*)carve((size_t)KSEL * 4);
    float*    boxes  = (float*)carve((size_t)KSEL * 16);
    uint64_t* mask   = (uint64_t*)carve((size_t)KSEL * 32 * 8);    // 0.52 MB
    (void)ws_size; (void)in_sizes; (void)n_in; (void)out_size;

    hipMemsetAsync(hist, 0, (size_t)HIST_SIZE * 4, stream);
    hipMemsetAsync(ctl, 0, 256, stream);

    transpose_w1<<<(9 * 512 * 512 + 255) / 256, 256, 0, stream>>>(w1, wT);
    conv_fused<<<dim3(NW / 16, NH / 4, NB), 256, 0, stream>>>(
        x, wT, b1, wcls, bcls, wreg, breg, scores, regs);
    hist_k<<<NPIX / 256, 256, 0, stream>>>(scores, hist);
    scan_k<<<1, 1024, 0, stream>>>(hist, ctl);
    collect_k<<<NPIX / 256, 256, 0, stream>>>(scores, ctl, cand);
    sort_decode_k<<<1, 1024, 0, stream>>>(cand, ctl, regs, hp, wp, tops_s, boxes);
    iou_k<<<dim3(KSEL / 64, KSEL / 64), 64, 0, stream>>>(boxes, mask);
    nms_k<<<1, 64, 0, stream>>>(tops_s, boxes, mask, out);
}

// Round 2
// 1798.239 us; speedup vs baseline: 1.4715x; 1.4715x over previous
//
#include <hip/hip_runtime.h>
#include <stdint.h>

#define NB 4
#define NC 512
#define NH 64
#define NW 96
#define NA 9
#define NPIX (NB*NA*NH*NW)   // 221184
#define KSEL 2048
#define NOUT 50
#define THRS 0.05f

#define HIST_BASE 0x3D4CCu   // bits(0.05f)>>12
#define HIST_SIZE 9024
#define CAND_CAP 8192

typedef _Float16 half8 __attribute__((ext_vector_type(8)));
typedef float floatx16 __attribute__((ext_vector_type(16)));

__device__ const float ANC_W[9] = {128.f,128.f,256.f,256.f,256.f,512.f,512.f,512.f,1024.f};
__device__ const float ANC_H[9] = {128.f,256.f,128.f,256.f,512.f,256.f,512.f,1024.f,512.f};

// ============ weight expand: w1[co][ci][3][3] fp32 -> wexp[kk][cc][co][8 slot16]
// slot s (0..5): step=s>>1 (0:wh 1:wl 2:wh), half=s&1 -> ci_l = half*8+j
// physical slot = s ^ (co&7)  (bank swizzle); values pre-scaled by 1024.
__global__ void wexp_k(const float* __restrict__ w1, uint4* __restrict__ wexp) {
    const int gid = blockIdx.x * 256 + threadIdx.x;
    if (gid >= 9 * 32 * 512) return;
    const int kk = gid >> 14;
    const int cc = (gid >> 9) & 31;
    const int co = gid & 511;
    const float* wrow = w1 + ((size_t)co * 512 + cc * 16) * 9 + kk;
    _Float16 wh[16], wl[16];
#pragma unroll
    for (int i = 0; i < 16; ++i) {
        const float v = wrow[i * 9] * 1024.f;
        wh[i] = (_Float16)v;
        wl[i] = (_Float16)(v - (float)wh[i]);
    }
    uint4* out = wexp + (size_t)gid * 8;
#pragma unroll
    for (int s = 0; s < 8; ++s) {
        union { _Float16 h[8]; uint4 u; } pk;
        if (s < 6) {
            const int step = s >> 1, hf = s & 1;
#pragma unroll
            for (int j = 0; j < 8; ++j) {
                const int ci = hf * 8 + j;
                pk.h[j] = (step == 1) ? wl[ci] : wh[ci];
            }
        } else {
            pk.u = make_uint4(0, 0, 0, 0);
        }
        out[s ^ (co & 7)] = pk.u;
    }
}

// ============ conv3x3 via fp16 MFMA, 3-term error-compensated split ============
// grid 256 blocks: bid&1 = co-half (256 co), bid>>1 = px-block (b, 8 rows x 24 cols)
// block 512 thr = 8 waves: wave = (px-half 96px) x (co-quarter 64co)
// per wave: 3 m-tiles x 2 n-tiles of 32x32, K = 9 taps x 32 ci-chunks x 48 slots
#define XS_BYTES 20800           // 260 px-slots * 80B ([16 xh][16 xl] + 16B pad)
#define WB_OFF   20800
#define CONV_LDS (20800 + 32768)

__global__ __launch_bounds__(512, 2) void conv_mfma(
    const float* __restrict__ x, const uint4* __restrict__ wexp,
    const float* __restrict__ b1, float* __restrict__ f)
{
    __shared__ __align__(16) char smem[CONV_LDS];
    char* xs = smem;
    char* wb = smem + WB_OFF;
    const int t = threadIdx.x;
    const int bid = blockIdx.x;
    const int half = bid & 1, pxb = bid >> 1;
    const int b = pxb >> 5, r = pxb & 31, by = r >> 2, bx = r & 3;
    const int y0 = by * 8, x0 = bx * 24;
    const int wave = t >> 6, lane = t & 63;
    const int hpx = wave >> 2, q = wave & 3;
    const int m32 = lane & 31, khalf = lane >> 5;

    int abase[3];
#pragma unroll
    for (int mt = 0; mt < 3; ++mt) {
        const int px = hpx * 96 + mt * 32 + m32;
        const int yl = px / 24, xl = px - yl * 24;
        abase[mt] = (yl * 26 + xl) * 80 + khalf * 16;
    }
    const int coL0 = q * 64 + m32;           // + nt*32; &7 == m32&7

    floatx16 acc[3][2];
#pragma unroll
    for (int mt = 0; mt < 3; ++mt)
#pragma unroll
        for (int nt = 0; nt < 2; ++nt)
#pragma unroll
            for (int i = 0; i < 16; ++i) acc[mt][nt][i] = 0.f;

    uint4 wr4[4];
    auto prefetch = [&](int qc) {
        const int cc2 = qc / 9, kk2 = qc - cc2 * 9;
        const uint4* src = wexp + ((size_t)(kk2 * 32 + cc2) * 512 + half * 256) * 8;
#pragma unroll
        for (int i = 0; i < 4; ++i) wr4[i] = src[t + i * 512];
    };

    prefetch(0);
    int qi = 0;
    for (int cc = 0; cc < 32; ++cc) {
        __syncthreads();                       // prev compute done: xs + wb free
        {   // stage x chunk: 16 ci, 10x26 halo px, fp16 hi/lo, scaled by 1024
            const float* xb = x + ((size_t)b * NC + cc * 16) * (NH * NW);
            for (int e = t; e < 4160; e += 512) {
                const int ci = e / 260;
                const int p = e - ci * 260;
                const int ya = p / 26, xa = p - ya * 26;
                const int gy = y0 - 1 + ya, gx = x0 - 1 + xa;
                float v = 0.f;
                if (gy >= 0 && gy < NH && gx >= 0 && gx < NW)
                    v = xb[ci * (NH * NW) + gy * NW + gx];
                v *= 1024.f;
                const _Float16 hh = (_Float16)v;
                const _Float16 ll = (_Float16)(v - (float)hh);
                char* base = xs + (ya * 26 + xa) * 80 + ci * 2;
                *(_Float16*)base = hh;
                *(_Float16*)(base + 32) = ll;
            }
        }
        for (int kk = 0; kk < 9; ++kk) {
            if (kk) __syncthreads();           // wb consumed by prev compute
            // commit prefetched weight chunk to LDS
#pragma unroll
            for (int i = 0; i < 4; ++i)
                *(uint4*)(wb + (t + i * 512) * 16) = wr4[i];
            prefetch(qi < 287 ? qi + 1 : 287);
            __syncthreads();                   // wb (and xs on kk==0) visible
            // compute: 3 k-steps (xh*wh, xh*wl, xl*wh) x 3 m x 2 n
            const int ky = kk / 3, kx = kk - ky * 3;
            const int koff = (ky * 26 + kx) * 80;
            half8 axh[3], axl[3];
#pragma unroll
            for (int mt = 0; mt < 3; ++mt) {
                axh[mt] = *(const half8*)(xs + abase[mt] + koff);
                axl[mt] = *(const half8*)(xs + abase[mt] + koff + 32);
            }
#pragma unroll
            for (int step = 0; step < 3; ++step) {
                half8 bf[2];
#pragma unroll
                for (int nt = 0; nt < 2; ++nt) {
                    const int coL = coL0 + nt * 32;
                    const int slot = (step * 2 + khalf) ^ (coL & 7);
                    bf[nt] = *(const half8*)(wb + coL * 128 + slot * 16);
                }
#pragma unroll
                for (int mt = 0; mt < 3; ++mt) {
                    const half8 av = (step == 2) ? axl[mt] : axh[mt];
#pragma unroll
                    for (int nt = 0; nt < 2; ++nt)
                        acc[mt][nt] = __builtin_amdgcn_mfma_f32_32x32x16_f16(
                            av, bf[nt], acc[mt][nt], 0, 0, 0);
                }
            }
            ++qi;
        }
    }

    // epilogue: descale 2^-20, + bias, store f[px][co]
    const float inv = 1.0f / 1048576.0f;
#pragma unroll
    for (int mt = 0; mt < 3; ++mt)
#pragma unroll
        for (int nt = 0; nt < 2; ++nt) {
            const int co = half * 256 + q * 64 + nt * 32 + m32;
            const float bias = b1[co];
#pragma unroll
            for (int reg = 0; reg < 16; ++reg) {
                const int row = (reg & 3) + 8 * (reg >> 2) + 4 * khalf;
                const int pxl = hpx * 96 + mt * 32 + row;
                const int yl = pxl / 24, xl = pxl - yl * 24;
                const size_t gpx = (size_t)(b * 64 + y0 + yl) * 96 + (x0 + xl);
                f[gpx * 512 + co] = acc[mt][nt][reg] * inv + bias;
            }
        }
}

// ============ heads: partial logits over a 128-ci quarter ============
// grid (96 px-blocks, 4 ci-quarters), block 256 thr (thread = px)
__global__ __launch_bounds__(256) void head_k(
    const float* __restrict__ f, const float* __restrict__ wcls,
    const float* __restrict__ wreg, float* __restrict__ part)
{
    __shared__ __align__(16) float smem[14336];  // 57344 B
    float* ftile = smem;                 // [256][36]
    float* wls = smem + 256 * 36;        // [54][32]
    const int t = threadIdx.x;
    const int px0 = blockIdx.x * 256;
    const int qd = blockIdx.y;
    float acc[54];
#pragma unroll
    for (int oc = 0; oc < 54; ++oc) acc[oc] = 0.f;

    for (int sub = 0; sub < 4; ++sub) {
        const int ci0 = qd * 128 + sub * 32;
        __syncthreads();
        for (int e = t; e < 8192; e += 256) {
            const int p = e >> 5, c = e & 31;
            ftile[p * 36 + c] = f[(size_t)(px0 + p) * 512 + ci0 + c];
        }
        for (int e = t; e < 1728; e += 256) {
            const int oc = e >> 5, c = e & 31;
            wls[oc * 32 + c] = (oc < 18) ? wcls[oc * 512 + ci0 + c]
                                         : wreg[(oc - 18) * 512 + ci0 + c];
        }
        __syncthreads();
        float fr[32];
#pragma unroll
        for (int c4 = 0; c4 < 8; ++c4) {
            const float4 v = *(const float4*)&ftile[t * 36 + c4 * 4];
            fr[c4 * 4 + 0] = v.x; fr[c4 * 4 + 1] = v.y;
            fr[c4 * 4 + 2] = v.z; fr[c4 * 4 + 3] = v.w;
        }
#pragma unroll
        for (int oc = 0; oc < 54; ++oc) {
            const float4* wrow = (const float4*)&wls[oc * 32];
            float s = 0.f;
#pragma unroll
            for (int c4 = 0; c4 < 8; ++c4) {
                const float4 wv = wrow[c4];
                s += fr[c4 * 4 + 0] * wv.x + fr[c4 * 4 + 1] * wv.y +
                     fr[c4 * 4 + 2] * wv.z + fr[c4 * 4 + 3] * wv.w;
            }
            acc[oc] += s;
        }
    }
    __syncthreads();
    float* otile = smem;                 // [256][56]
#pragma unroll
    for (int oc = 0; oc < 54; ++oc) otile[t * 56 + oc] = acc[oc];
    __syncthreads();
    for (int e = t; e < 14336; e += 256) {
        const int oc = e >> 8, p = e & 255;
        part[(size_t)(qd * 56 + oc) * 24576 + px0 + p] = otile[p * 56 + oc];
    }
}

// ============ combine partials + softmax -> scores, regs ============
__global__ __launch_bounds__(256) void combine_k(
    const float* __restrict__ part, const float* __restrict__ bcls,
    const float* __restrict__ breg, float* __restrict__ scores,
    float* __restrict__ regs)
{
    const int px = blockIdx.x * 256 + threadIdx.x;
    float lg[54];
#pragma unroll
    for (int oc = 0; oc < 54; ++oc) {
        float s = 0.f;
#pragma unroll
        for (int qd = 0; qd < 4; ++qd)
            s += part[(size_t)(qd * 56 + oc) * 24576 + px];
        lg[oc] = s;
    }
    float cl[18];
    float m = -1e30f;
#pragma unroll
    for (int oc = 0; oc < 18; ++oc) {
        cl[oc] = lg[oc] + bcls[oc];
        m = fmaxf(m, cl[oc]);
    }
    float sum = 0.f;
#pragma unroll
    for (int oc = 0; oc < 18; ++oc) { cl[oc] = expf(cl[oc] - m); sum += cl[oc]; }
    const float inv = 1.f / sum;
    const int b = px / 6144;
    const int yx = px - b * 6144;
#pragma unroll
    for (int a = 0; a < 9; ++a) {
        const int idx = b * 55296 + a * 6144 + yx;
        scores[idx] = cl[2 * a + 1] * inv;
        float4 rv;
        rv.x = lg[18 + a * 4 + 0] + breg[a * 4 + 0];
        rv.y = lg[18 + a * 4 + 1] + breg[a * 4 + 1];
        rv.z = lg[18 + a * 4 + 2] + breg[a * 4 + 2];
        rv.w = lg[18 + a * 4 + 3] + breg[a * 4 + 3];
        ((float4*)regs)[idx] = rv;
    }
}

// ---------------- histogram over score float bits ----------------
__global__ void hist_k(const float* __restrict__ scores, uint32_t* __restrict__ hist) {
    const int i = blockIdx.x * 256 + threadIdx.x;
    const float s = scores[i];
    if (s >= THRS) {
        int bkt = (int)(__float_as_uint(s) >> 12) - (int)HIST_BASE;
        bkt = min(max(bkt, 0), HIST_SIZE - 1);
        atomicAdd(&hist[bkt], 1u);
    }
}

// ---------------- suffix scan -> cutoff bucket ----------------
__global__ void scan_k(const uint32_t* __restrict__ hist, uint32_t* __restrict__ ctl) {
    __shared__ uint32_t ssum[1024];
    const int t = threadIdx.x;
    uint32_t s = 0;
#pragma unroll
    for (int u = 0; u < 9; ++u) {
        const int bkt = t * 9 + u;
        if (bkt < HIST_SIZE) s += hist[bkt];
    }
    const uint32_t mysum = s;
    ssum[t] = s;
    __syncthreads();
    for (int off = 1; off < 1024; off <<= 1) {
        uint32_t v = (t + off < 1024) ? ssum[t + off] : 0u;
        __syncthreads();
        ssum[t] += v;
        __syncthreads();
    }
    const uint32_t total = ssum[0];
    const uint32_t above = (t < 1023) ? ssum[t + 1] : 0u;
    if (total < KSEL) {
        if (t == 0) ctl[0] = HIST_BASE;
    } else if (above < KSEL && above + mysum >= KSEL) {
        uint32_t run = above;
        for (int u = 8; u >= 0; --u) {
            const int bkt = t * 9 + u;
            if (bkt >= HIST_SIZE) continue;
            run += hist[bkt];
            if (run >= KSEL) { ctl[0] = HIST_BASE + (uint32_t)bkt; break; }
        }
    }
}

// ---------------- compact candidates above cutoff ----------------
__global__ void collect_k(const float* __restrict__ scores, uint32_t* __restrict__ ctl,
                          uint64_t* __restrict__ cand) {
    const int i = blockIdx.x * 256 + threadIdx.x;
    const float s = scores[i];
    if (s >= THRS) {
        const uint32_t bits = __float_as_uint(s);
        if ((bits >> 12) >= ctl[0]) {
            const uint32_t pos = atomicAdd(&ctl[1], 1u);
            if (pos < CAND_CAP)
                cand[pos] = ((uint64_t)bits << 32) | (uint64_t)(0xFFFFFFFFu - (uint32_t)i);
        }
    }
}

// ---------------- single-block bitonic sort (desc) + box decode ----------------
__global__ void sort_decode_k(const uint64_t* __restrict__ cand, const uint32_t* __restrict__ ctl,
                              const float* __restrict__ regs,
                              const int* __restrict__ hp, const int* __restrict__ wp,
                              float* __restrict__ tops_s, float* __restrict__ boxes) {
    __shared__ uint64_t keys[CAND_CAP];
    const int t = threadIdx.x;
    const int M = min((int)ctl[1], CAND_CAP);
    const int N = (M <= 4096) ? 4096 : 8192;
    for (int k = t; k < N; k += 1024) keys[k] = (k < M) ? cand[k] : 0ull;
    __syncthreads();
    for (int size = 2; size <= N; size <<= 1) {
        for (int stride = size >> 1; stride > 0; stride >>= 1) {
            for (int k = t; k < N; k += 1024) {
                const int p = k ^ stride;
                if (p > k) {
                    const uint64_t a = keys[k], bb = keys[p];
                    const bool sw = ((k & size) == 0) ? (a < bb) : (a > bb);
                    if (sw) { keys[k] = bb; keys[p] = a; }
                }
            }
            __syncthreads();
        }
    }
    const int w_in = wp[0], h_in = hp[0];
    const float offx = (float)((w_in - 16) % 16) * 0.5f + 8.0f;
    const float offy = (float)((h_in - 16) % 16) * 0.5f + 8.0f;
    for (int k = t; k < KSEL; k += 1024) {
        const uint64_t key = keys[k];
        float sc = -1.f, x1 = 0.f, y1 = 0.f, x2 = 0.f, y2 = 0.f;
        if (k < M && key != 0ull) {
            const uint32_t idx = 0xFFFFFFFFu - (uint32_t)(key & 0xFFFFFFFFull);
            sc = __uint_as_float((uint32_t)(key >> 32));
            const int a  = (int)(idx / (NH * NW)) % NA;
            const int yy = (int)(idx / NW) % NH;
            const int xx = (int)(idx % NW);
            const float4 r = ((const float4*)regs)[idx];
            const float aw = ANC_W[a], ah = ANC_H[a];
            const float cx = (float)xx * 16.f + offx;
            const float cy = (float)yy * 16.f + offy;
            const float bx = r.x * aw + cx;
            const float by = r.y * ah + cy;
            const float bw = expf(r.z) * aw;
            const float bh = expf(r.w) * ah;
            x1 = bx - bw * 0.5f; y1 = by - bh * 0.5f;
            x2 = bx + bw * 0.5f; y2 = by + bh * 0.5f;
        }
        tops_s[k] = sc;
        ((float4*)boxes)[k] = make_float4(x1, y1, x2, y2);
    }
}

// ---------------- pairwise IoU suppression bitmask ----------------
__global__ void iou_k(const float* __restrict__ boxes, uint64_t* __restrict__ mask) {
    __shared__ float4 jb[64];
    const int t = threadIdx.x;
    const int bi = blockIdx.x, bj = blockIdx.y;
    jb[t] = ((const float4*)boxes)[bj * 64 + t];
    __syncthreads();
    const int i = bi * 64 + t;
    const float4 mb = ((const float4*)boxes)[i];
    const float areai = (mb.z - mb.x) * (mb.w - mb.y);
    uint64_t w = 0;
    for (int jj = 0; jj < 64; ++jj) {
        const float4 ob = jb[jj];
        const int j = bj * 64 + jj;
        const float ix1 = fmaxf(mb.x, ob.x);
        const float iy1 = fmaxf(mb.y, ob.y);
        const float ix2 = fminf(mb.z, ob.z);
        const float iy2 = fminf(mb.w, ob.w);
        const float inter = fmaxf(ix2 - ix1, 0.f) * fmaxf(iy2 - iy1, 0.f);
        const float areaj = (ob.z - ob.x) * (ob.w - ob.y);
        const float iou = inter / (areai + areaj - inter + 1e-9f);
        if (iou > 0.7f && j > i) w |= (1ull << jj);
    }
    mask[(size_t)i * 32 + bj] = w;
}

// ---------------- sequential greedy NMS (single wave, no barriers) ----------------
__global__ void nms_k(const float* __restrict__ tops_s, const float* __restrict__ boxes,
                      const uint64_t* __restrict__ mask, float* __restrict__ out) {
    __shared__ uint64_t remv[32];
    __shared__ float ssc[KSEL];
    __shared__ int sel[NOUT];
    const int t = threadIdx.x;      // 64 threads = 1 wave: program order == LDS order
    for (int k = t; k < KSEL; k += 64) ssc[k] = tops_s[k];
    if (t < 32) remv[t] = 0ull;
    int cnt = 0;                    // wave-uniform
    for (int i = 0; i < KSEL; ++i) {
        const uint64_t rw = remv[i >> 6];
        const bool sup = (rw >> (i & 63)) & 1ull;
        const bool val = (ssc[i] >= THRS);
        if (val && !sup) {
            if (t < 32) remv[t] |= mask[(size_t)i * 32 + t];
            if (cnt < NOUT && t == 0) sel[cnt] = i;
            ++cnt;
        }
    }
    for (int k = t; k < NOUT; k += 64) {
        float s = 0.f;
        float4 bb = make_float4(0.f, 0.f, 0.f, 0.f);
        if (k < cnt) { const int i = sel[k]; s = ssc[i]; bb = ((const float4*)boxes)[i]; }
        out[k] = s;
        out[NOUT + k * 4 + 0] = bb.x;
        out[NOUT + k * 4 + 1] = bb.y;
        out[NOUT + k * 4 + 2] = bb.z;
        out[NOUT + k * 4 + 3] = bb.w;
    }
}

extern "C" void kernel_launch(void* const* d_in, const int* in_sizes, int n_in,
                              void* d_out, int out_size, void* d_ws, size_t ws_size,
                              hipStream_t stream) {
    const float* x    = (const float*)d_in[0];
    const float* w1   = (const float*)d_in[1];
    const float* b1   = (const float*)d_in[2];
    const float* wcls = (const float*)d_in[3];
    const float* bcls = (const float*)d_in[4];
    const float* wreg = (const float*)d_in[5];
    const float* breg = (const float*)d_in[6];
    const int*   hp   = (const int*)d_in[7];
    const int*   wp   = (const int*)d_in[8];
    float* out = (float*)d_out;

    char* ws = (char*)d_ws;
    size_t off = 0;
    auto carve = [&](size_t bytes) -> void* {
        void* p = ws + off;
        off = (off + bytes + 255) & ~(size_t)255;
        return p;
    };
    uint4*    wexp   = (uint4*)carve((size_t)9 * 32 * 512 * 128);      // 18.9 MB
    float*    f      = (float*)carve((size_t)24576 * 512 * 4);         // 50.3 MB
    float*    part   = (float*)carve((size_t)4 * 56 * 24576 * 4);      // 22.0 MB
    float*    scores = (float*)carve((size_t)NPIX * 4);
    float*    regs   = (float*)carve((size_t)NPIX * 16);
    uint32_t* hist   = (uint32_t*)carve((size_t)HIST_SIZE * 4);
    uint32_t* ctl    = (uint32_t*)carve(256);
    uint64_t* cand   = (uint64_t*)carve((size_t)CAND_CAP * 8);
    float*    tops_s = (float*)carve((size_t)KSEL * 4);
    float*    boxes  = (float*)carve((size_t)KSEL * 16);
    uint64_t* mask   = (uint64_t*)carve((size_t)KSEL * 32 * 8);
    (void)ws_size; (void)in_sizes; (void)n_in; (void)out_size;

    hipMemsetAsync(hist, 0, (size_t)HIST_SIZE * 4, stream);
    hipMemsetAsync(ctl, 0, 256, stream);

    wexp_k<<<576, 256, 0, stream>>>(w1, wexp);
    conv_mfma<<<256, 512, 0, stream>>>(x, wexp, b1, f);
    head_k<<<dim3(96, 4), 256, 0, stream>>>(f, wcls, wreg, part);
    combine_k<<<96, 256, 0, stream>>>(part, bcls, breg, scores, regs);
    hist_k<<<NPIX / 256, 256, 0, stream>>>(scores, hist);
    scan_k<<<1, 1024, 0, stream>>>(hist, ctl);
    collect_k<<<NPIX / 256, 256, 0, stream>>>(scores, ctl, cand);
    sort_decode_k<<<1, 1024, 0, stream>>>(cand, ctl, regs, hp, wp, tops_s, boxes);
    iou_k<<<dim3(KSEL / 64, KSEL / 64), 64, 0, stream>>>(boxes, mask);
    nms_k<<<1, 64, 0, stream>>>(tops_s, boxes, mask, out);
}

// Round 3
// 684.252 us; speedup vs baseline: 3.8671x; 2.6280x over previous
//
#include <hip/hip_runtime.h>
#include <stdint.h>

#define NB 4
#define NC 512
#define NH 64
#define NW 96
#define NA 9
#define NPIX (NB*NA*NH*NW)   // 221184
#define KSEL 2048
#define NOUT 50
#define THRS 0.05f

#define HIST_BASE 0x3D4CCu   // bits(0.05f)>>12
#define HIST_SIZE 9024
#define CAND_CAP 8192

typedef _Float16 half8 __attribute__((ext_vector_type(8)));
typedef float floatx16 __attribute__((ext_vector_type(16)));

__device__ const float ANC_W[9] = {128.f,128.f,256.f,256.f,256.f,512.f,512.f,512.f,1024.f};
__device__ const float ANC_H[9] = {128.f,256.f,128.f,256.f,512.f,256.f,512.f,1024.f,512.f};

// ============ weight expand (coalesced, LDS transpose) ============
// w1[co][ci][3][3] fp32 -> wexp2[(cc*9+kk)][kd(4)][co(512)] half8 (16B units)
// kd = kind*2 + khalf; kind0 = hi, kind1 = lo; values pre-scaled by 1024.
// grid 512 blocks: cc = bid>>4 (32), cog = bid&15 (16 groups of 32 co).
__global__ __launch_bounds__(256) void wexp2_k(const float* __restrict__ w1,
                                               uint4* __restrict__ wexp2) {
    __shared__ __align__(16) _Float16 lbuf[36 * 32 * 8];   // 18432 B
    const int bid = blockIdx.x;
    const int cc = bid >> 4, cog = bid & 15;
    const int t = threadIdx.x;
    const int co_l = t >> 3, j = t & 7;
    const int co = cog * 32 + co_l;
    const float* r0 = w1 + ((size_t)co * 512 + cc * 16 + j) * 9;      // ci = cc*16+j
    const float* r1 = r0 + 8 * 9;                                      // ci = cc*16+8+j
#pragma unroll
    for (int kk = 0; kk < 9; ++kk) {
        const float v0 = r0[kk] * 1024.f;
        const float v1 = r1[kk] * 1024.f;
        const _Float16 h0 = (_Float16)v0, h1 = (_Float16)v1;
        const _Float16 l0 = (_Float16)(v0 - (float)h0);
        const _Float16 l1 = (_Float16)(v1 - (float)h1);
        // entry (kk, kind, khalf, co_l) at ((kk*4+kind*2+khalf)*32 + co_l)*8 + j
        lbuf[((kk * 4 + 0) * 32 + co_l) * 8 + j] = h0;
        lbuf[((kk * 4 + 1) * 32 + co_l) * 8 + j] = h1;
        lbuf[((kk * 4 + 2) * 32 + co_l) * 8 + j] = l0;
        lbuf[((kk * 4 + 3) * 32 + co_l) * 8 + j] = l1;
    }
    __syncthreads();
    for (int e = t; e < 1152; e += 256) {
        const int co_e = e & 31;
        const int rest = e >> 5;            // kk*4 + kd (0..35)
        const int kk = rest >> 2, kd = rest & 3;
        const uint4 v = *(const uint4*)&lbuf[(rest * 32 + co_e) * 8];
        wexp2[(((size_t)(cc * 9 + kk) * 4 + kd) * 512) + cog * 32 + co_e] = v;
    }
}

// ============ conv3x3 via fp16 MFMA, 3-term split, pipelined K-loop ============
// grid 256: bid&1 = co-half (256 co), bid>>1 = px-block (b, 8 rows x 24 cols = 192 px)
// block 512 thr = 8 waves: (hpx 2) x (qc 4); wave tile 96 px (3 mt) x 64 co (2 nt)
// K chunks q = cc*9 + kk (288); per q: 18 MFMA; ONE barrier per q.
#define XS_BYTES 20800           // 260 slots * 80 B ([hi kh0][hi kh1][lo kh0][lo kh1][pad])
#define WB_BYTES 16384           // 4 planes * 256 co * 16 B
#define CONV_LDS (XS_BYTES + 2*WB_BYTES)

__global__ __launch_bounds__(512, 2) void conv_mfma(
    const float* __restrict__ x, const uint4* __restrict__ wexp2,
    const float* __restrict__ b1, float* __restrict__ f)
{
    __shared__ __align__(16) char smem[CONV_LDS];
    char* xs = smem;
    char* wb = smem + XS_BYTES;
    const int t = threadIdx.x;
    const int bid = blockIdx.x;
    const int half = bid & 1, pxb = bid >> 1;
    const int b = pxb >> 5, r = pxb & 31, by = r >> 2, bx = r & 3;
    const int y0 = by * 8, x0 = bx * 24;
    const int wq = t >> 6, lane = t & 63;
    const int hpx = wq >> 2, qc = wq & 3;
    const int m32 = lane & 31, khalf = lane >> 5;

    int abase[3];
#pragma unroll
    for (int mt = 0; mt < 3; ++mt) {
        const int px = hpx * 96 + mt * 32 + m32;
        const int yl = px / 24, xl = px - yl * 24;
        abase[mt] = (yl * 26 + xl) * 80 + khalf * 16;
    }
    const int bbase = khalf * 4096 + (qc * 64 + m32) * 16;   // + nt*512, + kind*8192

    floatx16 acc[3][2];
#pragma unroll
    for (int mt = 0; mt < 3; ++mt)
#pragma unroll
        for (int nt = 0; nt < 2; ++nt)
#pragma unroll
            for (int i = 0; i < 16; ++i) acc[mt][nt][i] = 0.f;

    // weight prefetch lanes: thread covers (kd=pp, co_l) and (kd=pp+2, co_l)
    const int co_l = t & 255, pp = t >> 8;
    const uint4* wsrc = wexp2 + half * 256 + co_l;
    uint4 pf0, pf1;
    auto loadw = [&](int q2) {
        const size_t base = (size_t)q2 * 2048;
        pf0 = wsrc[base + (size_t)pp * 512];
        pf1 = wsrc[base + (size_t)(pp + 2) * 512];
    };
    const int wa0 = pp * 4096 + co_l * 16;
    const int wa1 = (pp + 2) * 4096 + co_l * 16;

    const float* xb = x + (size_t)b * NC * (NH * NW);

    loadw(0);
    // pre-commit chunk 0 into buf 0 (no reader yet)
    *(uint4*)(wb + wa0) = pf0;
    *(uint4*)(wb + wa1) = pf1;
    loadw(1);

    int cc = 0, kk = 0;
    for (int q = 0; q < 288; ++q) {
        if (kk == 0) {
            __syncthreads();                 // prev-cc xs readers done
            // stage x chunk cc: 16 ci, 260 halo slots, hi/lo fp16, scaled 1024
            const float* xc = xb + (size_t)cc * 16 * (NH * NW);
            for (int it = t; it < 520; it += 512) {
                const int kh = (it >= 260) ? 1 : 0;
                const int slot = it - kh * 260;
                const int ya = slot / 26, xa = slot - ya * 26;
                const int gy = y0 - 1 + ya, gx = x0 - 1 + xa;
                const bool ok = (gy >= 0 && gy < NH && gx >= 0 && gx < NW);
                const int off = ok ? (kh * 8 * 6144 + gy * 96 + gx) : 0;
                union { _Float16 h[8]; uint4 u; } hi, lo;
#pragma unroll
                for (int j = 0; j < 8; ++j) {
                    const float v = (ok ? xc[off + j * 6144] : 0.f) * 1024.f;
                    const _Float16 hh = (_Float16)v;
                    hi.h[j] = hh;
                    lo.h[j] = (_Float16)(v - (float)hh);
                }
                *(uint4*)(xs + slot * 80 + kh * 16) = hi.u;
                *(uint4*)(xs + slot * 80 + 32 + kh * 16) = lo.u;
            }
        }
        __syncthreads();                     // wb[q&1] + xs visible; wb[(q+1)&1] free
        if (q < 287) {
            char* wd = wb + ((q + 1) & 1) * WB_BYTES;
            *(uint4*)(wd + wa0) = pf0;       // commit chunk q+1
            *(uint4*)(wd + wa1) = pf1;
            if (q < 286) loadw(q + 2);       // prefetch chunk q+2 (full interval to land)
        }
        // ---- compute chunk q ----
        {
            const int ky = kk / 3, kx = kk - ky * 3;
            const char* xcur = xs + (ky * 26 + kx) * 80;
            half8 axh[3], axl[3];
#pragma unroll
            for (int mt = 0; mt < 3; ++mt) {
                axh[mt] = *(const half8*)(xcur + abase[mt]);
                axl[mt] = *(const half8*)(xcur + abase[mt] + 32);
            }
            const char* wc = wb + (q & 1) * WB_BYTES + bbase;
            half8 bwh[2], bwl[2];
#pragma unroll
            for (int nt = 0; nt < 2; ++nt) {
                bwh[nt] = *(const half8*)(wc + nt * 512);
                bwl[nt] = *(const half8*)(wc + 8192 + nt * 512);
            }
#pragma unroll
            for (int nt = 0; nt < 2; ++nt)
#pragma unroll
                for (int mt = 0; mt < 3; ++mt)
                    acc[mt][nt] = __builtin_amdgcn_mfma_f32_32x32x16_f16(
                        axh[mt], bwh[nt], acc[mt][nt], 0, 0, 0);
#pragma unroll
            for (int nt = 0; nt < 2; ++nt)
#pragma unroll
                for (int mt = 0; mt < 3; ++mt)
                    acc[mt][nt] = __builtin_amdgcn_mfma_f32_32x32x16_f16(
                        axh[mt], bwl[nt], acc[mt][nt], 0, 0, 0);
#pragma unroll
            for (int nt = 0; nt < 2; ++nt)
#pragma unroll
                for (int mt = 0; mt < 3; ++mt)
                    acc[mt][nt] = __builtin_amdgcn_mfma_f32_32x32x16_f16(
                        axl[mt], bwh[nt], acc[mt][nt], 0, 0, 0);
        }
        if (++kk == 9) { kk = 0; ++cc; }
    }

    // epilogue: descale 2^-20, + bias, store f[px][co]
    const float inv = 1.0f / 1048576.0f;
#pragma unroll
    for (int mt = 0; mt < 3; ++mt)
#pragma unroll
        for (int nt = 0; nt < 2; ++nt) {
            const int co = half * 256 + qc * 64 + nt * 32 + m32;
            const float bias = b1[co];
#pragma unroll
            for (int reg = 0; reg < 16; ++reg) {
                const int row = (reg & 3) + 8 * (reg >> 2) + 4 * khalf;
                const int pxl = hpx * 96 + mt * 32 + row;
                const int yl = pxl / 24, xl = pxl - yl * 24;
                const size_t gpx = (size_t)(b * 64 + y0 + yl) * 96 + (x0 + xl);
                f[gpx * 512 + co] = acc[mt][nt][reg] * inv + bias;
            }
        }
}

// ============ heads: partial logits over a 128-ci quarter ============
__global__ __launch_bounds__(256) void head_k(
    const float* __restrict__ f, const float* __restrict__ wcls,
    const float* __restrict__ wreg, float* __restrict__ part)
{
    __shared__ __align__(16) float smem[14336];  // 57344 B
    float* ftile = smem;                 // [256][36]
    float* wls = smem + 256 * 36;        // [54][32]
    const int t = threadIdx.x;
    const int px0 = blockIdx.x * 256;
    const int qd = blockIdx.y;
    float acc[54];
#pragma unroll
    for (int oc = 0; oc < 54; ++oc) acc[oc] = 0.f;

    for (int sub = 0; sub < 4; ++sub) {
        const int ci0 = qd * 128 + sub * 32;
        __syncthreads();
        for (int e = t; e < 8192; e += 256) {
            const int p = e >> 5, c = e & 31;
            ftile[p * 36 + c] = f[(size_t)(px0 + p) * 512 + ci0 + c];
        }
        for (int e = t; e < 1728; e += 256) {
            const int oc = e >> 5, c = e & 31;
            wls[oc * 32 + c] = (oc < 18) ? wcls[oc * 512 + ci0 + c]
                                         : wreg[(oc - 18) * 512 + ci0 + c];
        }
        __syncthreads();
        float fr[32];
#pragma unroll
        for (int c4 = 0; c4 < 8; ++c4) {
            const float4 v = *(const float4*)&ftile[t * 36 + c4 * 4];
            fr[c4 * 4 + 0] = v.x; fr[c4 * 4 + 1] = v.y;
            fr[c4 * 4 + 2] = v.z; fr[c4 * 4 + 3] = v.w;
        }
#pragma unroll
        for (int oc = 0; oc < 54; ++oc) {
            const float4* wrow = (const float4*)&wls[oc * 32];
            float s = 0.f;
#pragma unroll
            for (int c4 = 0; c4 < 8; ++c4) {
                const float4 wv = wrow[c4];
                s += fr[c4 * 4 + 0] * wv.x + fr[c4 * 4 + 1] * wv.y +
                     fr[c4 * 4 + 2] * wv.z + fr[c4 * 4 + 3] * wv.w;
            }
            acc[oc] += s;
        }
    }
    __syncthreads();
    float* otile = smem;                 // [256][56]
#pragma unroll
    for (int oc = 0; oc < 54; ++oc) otile[t * 56 + oc] = acc[oc];
    __syncthreads();
    for (int e = t; e < 14336; e += 256) {
        const int oc = e >> 8, p = e & 255;
        part[(size_t)(qd * 56 + oc) * 24576 + px0 + p] = otile[p * 56 + oc];
    }
}

// ============ combine partials + softmax -> scores, regs ============
__global__ __launch_bounds__(256) void combine_k(
    const float* __restrict__ part, const float* __restrict__ bcls,
    const float* __restrict__ breg, float* __restrict__ scores,
    float* __restrict__ regs)
{
    const int px = blockIdx.x * 256 + threadIdx.x;
    float lg[54];
#pragma unroll
    for (int oc = 0; oc < 54; ++oc) {
        float s = 0.f;
#pragma unroll
        for (int qd = 0; qd < 4; ++qd)
            s += part[(size_t)(qd * 56 + oc) * 24576 + px];
        lg[oc] = s;
    }
    float cl[18];
    float m = -1e30f;
#pragma unroll
    for (int oc = 0; oc < 18; ++oc) {
        cl[oc] = lg[oc] + bcls[oc];
        m = fmaxf(m, cl[oc]);
    }
    float sum = 0.f;
#pragma unroll
    for (int oc = 0; oc < 18; ++oc) { cl[oc] = expf(cl[oc] - m); sum += cl[oc]; }
    const float inv = 1.f / sum;
    const int b = px / 6144;
    const int yx = px - b * 6144;
#pragma unroll
    for (int a = 0; a < 9; ++a) {
        const int idx = b * 55296 + a * 6144 + yx;
        scores[idx] = cl[2 * a + 1] * inv;
        float4 rv;
        rv.x = lg[18 + a * 4 + 0] + breg[a * 4 + 0];
        rv.y = lg[18 + a * 4 + 1] + breg[a * 4 + 1];
        rv.z = lg[18 + a * 4 + 2] + breg[a * 4 + 2];
        rv.w = lg[18 + a * 4 + 3] + breg[a * 4 + 3];
        ((float4*)regs)[idx] = rv;
    }
}

// ---------------- histogram over score float bits ----------------
__global__ void hist_k(const float* __restrict__ scores, uint32_t* __restrict__ hist) {
    const int i = blockIdx.x * 256 + threadIdx.x;
    const float s = scores[i];
    if (s >= THRS) {
        int bkt = (int)(__float_as_uint(s) >> 12) - (int)HIST_BASE;
        bkt = min(max(bkt, 0), HIST_SIZE - 1);
        atomicAdd(&hist[bkt], 1u);
    }
}

// ---------------- suffix scan -> cutoff bucket ----------------
__global__ void scan_k(const uint32_t* __restrict__ hist, uint32_t* __restrict__ ctl) {
    __shared__ uint32_t ssum[1024];
    const int t = threadIdx.x;
    uint32_t s = 0;
#pragma unroll
    for (int u = 0; u < 9; ++u) {
        const int bkt = t * 9 + u;
        if (bkt < HIST_SIZE) s += hist[bkt];
    }
    const uint32_t mysum = s;
    ssum[t] = s;
    __syncthreads();
    for (int off = 1; off < 1024; off <<= 1) {
        uint32_t v = (t + off < 1024) ? ssum[t + off] : 0u;
        __syncthreads();
        ssum[t] += v;
        __syncthreads();
    }
    const uint32_t total = ssum[0];
    const uint32_t above = (t < 1023) ? ssum[t + 1] : 0u;
    if (total < KSEL) {
        if (t == 0) ctl[0] = HIST_BASE;
    } else if (above < KSEL && above + mysum >= KSEL) {
        uint32_t run = above;
        for (int u = 8; u >= 0; --u) {
            const int bkt = t * 9 + u;
            if (bkt >= HIST_SIZE) continue;
            run += hist[bkt];
            if (run >= KSEL) { ctl[0] = HIST_BASE + (uint32_t)bkt; break; }
        }
    }
}

// ---------------- compact candidates above cutoff ----------------
__global__ void collect_k(const float* __restrict__ scores, uint32_t* __restrict__ ctl,
                          uint64_t* __restrict__ cand) {
    const int i = blockIdx.x * 256 + threadIdx.x;
    const float s = scores[i];
    if (s >= THRS) {
        const uint32_t bits = __float_as_uint(s);
        if ((bits >> 12) >= ctl[0]) {
            const uint32_t pos = atomicAdd(&ctl[1], 1u);
            if (pos < CAND_CAP)
                cand[pos] = ((uint64_t)bits << 32) | (uint64_t)(0xFFFFFFFFu - (uint32_t)i);
        }
    }
}

// ---------------- single-block bitonic sort (desc) + box decode ----------------
__global__ void sort_decode_k(const uint64_t* __restrict__ cand, const uint32_t* __restrict__ ctl,
                              const float* __restrict__ regs,
                              const int* __restrict__ hp, const int* __restrict__ wp,
                              float* __restrict__ tops_s, float* __restrict__ boxes) {
    __shared__ uint64_t keys[CAND_CAP];
    const int t = threadIdx.x;
    const int M = min((int)ctl[1], CAND_CAP);
    const int N = (M <= 4096) ? 4096 : 8192;
    for (int k = t; k < N; k += 1024) keys[k] = (k < M) ? cand[k] : 0ull;
    __syncthreads();
    for (int size = 2; size <= N; size <<= 1) {
        for (int stride = size >> 1; stride > 0; stride >>= 1) {
            for (int k = t; k < N; k += 1024) {
                const int p = k ^ stride;
                if (p > k) {
                    const uint64_t a = keys[k], bb = keys[p];
                    const bool sw = ((k & size) == 0) ? (a < bb) : (a > bb);
                    if (sw) { keys[k] = bb; keys[p] = a; }
                }
            }
            __syncthreads();
        }
    }
    const int w_in = wp[0], h_in = hp[0];
    const float offx = (float)((w_in - 16) % 16) * 0.5f + 8.0f;
    const float offy = (float)((h_in - 16) % 16) * 0.5f + 8.0f;
    for (int k = t; k < KSEL; k += 1024) {
        const uint64_t key = keys[k];
        float sc = -1.f, x1 = 0.f, y1 = 0.f, x2 = 0.f, y2 = 0.f;
        if (k < M && key != 0ull) {
            const uint32_t idx = 0xFFFFFFFFu - (uint32_t)(key & 0xFFFFFFFFull);
            sc = __uint_as_float((uint32_t)(key >> 32));
            const int a  = (int)(idx / (NH * NW)) % NA;
            const int yy = (int)(idx / NW) % NH;
            const int xx = (int)(idx % NW);
            const float4 r = ((const float4*)regs)[idx];
            const float aw = ANC_W[a], ah = ANC_H[a];
            const float cx = (float)xx * 16.f + offx;
            const float cy = (float)yy * 16.f + offy;
            const float bx = r.x * aw + cx;
            const float by = r.y * ah + cy;
            const float bw = expf(r.z) * aw;
            const float bh = expf(r.w) * ah;
            x1 = bx - bw * 0.5f; y1 = by - bh * 0.5f;
            x2 = bx + bw * 0.5f; y2 = by + bh * 0.5f;
        }
        tops_s[k] = sc;
        ((float4*)boxes)[k] = make_float4(x1, y1, x2, y2);
    }
}

// ---------------- pairwise IoU suppression bitmask ----------------
__global__ void iou_k(const float* __restrict__ boxes, uint64_t* __restrict__ mask) {
    __shared__ float4 jb[64];
    const int t = threadIdx.x;
    const int bi = blockIdx.x, bj = blockIdx.y;
    jb[t] = ((const float4*)boxes)[bj * 64 + t];
    __syncthreads();
    const int i = bi * 64 + t;
    const float4 mb = ((const float4*)boxes)[i];
    const float areai = (mb.z - mb.x) * (mb.w - mb.y);
    uint64_t w = 0;
    for (int jj = 0; jj < 64; ++jj) {
        const float4 ob = jb[jj];
        const int j = bj * 64 + jj;
        const float ix1 = fmaxf(mb.x, ob.x);
        const float iy1 = fmaxf(mb.y, ob.y);
        const float ix2 = fminf(mb.z, ob.z);
        const float iy2 = fminf(mb.w, ob.w);
        const float inter = fmaxf(ix2 - ix1, 0.f) * fmaxf(iy2 - iy1, 0.f);
        const float areaj = (ob.z - ob.x) * (ob.w - ob.y);
        const float iou = inter / (areai + areaj - inter + 1e-9f);
        if (iou > 0.7f && j > i) w |= (1ull << jj);
    }
    mask[(size_t)i * 32 + bj] = w;
}

// ---------------- sequential greedy NMS (single wave, early exit, prefetch) ----------------
__global__ void nms_k(const float* __restrict__ tops_s, const float* __restrict__ boxes,
                      const uint64_t* __restrict__ mask, float* __restrict__ out) {
    __shared__ uint64_t remv[32];
    __shared__ float ssc[KSEL];
    __shared__ int sel[NOUT];
    const int t = threadIdx.x;      // 64 threads = 1 wave
    for (int k = t; k < KSEL; k += 64) ssc[k] = tops_s[k];
    if (t < 32) remv[t] = 0ull;
    uint64_t nextrow = (t < 32) ? mask[t] : 0ull;   // row 0 prefetch
    int cnt = 0;                    // wave-uniform
    for (int i = 0; i < KSEL && cnt < NOUT; ++i) {
        const uint64_t cur = nextrow;
        if (t < 32 && i + 1 < KSEL) nextrow = mask[(size_t)(i + 1) * 32 + t];
        const uint64_t rw = remv[i >> 6];
        const bool sup = (rw >> (i & 63)) & 1ull;
        if (ssc[i] >= THRS && !sup) {
            if (t < 32) remv[t] |= cur;
            if (t == 0) sel[cnt] = i;
            ++cnt;
        }
    }
    for (int k = t; k < NOUT; k += 64) {
        float s = 0.f;
        float4 bb = make_float4(0.f, 0.f, 0.f, 0.f);
        if (k < cnt) { const int i = sel[k]; s = ssc[i]; bb = ((const float4*)boxes)[i]; }
        out[k] = s;
        out[NOUT + k * 4 + 0] = bb.x;
        out[NOUT + k * 4 + 1] = bb.y;
        out[NOUT + k * 4 + 2] = bb.z;
        out[NOUT + k * 4 + 3] = bb.w;
    }
}

extern "C" void kernel_launch(void* const* d_in, const int* in_sizes, int n_in,
                              void* d_out, int out_size, void* d_ws, size_t ws_size,
                              hipStream_t stream) {
    const float* x    = (const float*)d_in[0];
    const float* w1   = (const float*)d_in[1];
    const float* b1   = (const float*)d_in[2];
    const float* wcls = (const float*)d_in[3];
    const float* bcls = (const float*)d_in[4];
    const float* wreg = (const float*)d_in[5];
    const float* breg = (const float*)d_in[6];
    const int*   hp   = (const int*)d_in[7];
    const int*   wp   = (const int*)d_in[8];
    float* out = (float*)d_out;

    char* ws = (char*)d_ws;
    size_t off = 0;
    auto carve = [&](size_t bytes) -> void* {
        void* p = ws + off;
        off = (off + bytes + 255) & ~(size_t)255;
        return p;
    };
    uint4*    wexp2  = (uint4*)carve((size_t)288 * 4 * 512 * 16);      // 9.44 MB
    float*    f      = (float*)carve((size_t)24576 * 512 * 4);         // 50.3 MB
    float*    part   = (float*)carve((size_t)4 * 56 * 24576 * 4);      // 22.0 MB
    float*    scores = (float*)carve((size_t)NPIX * 4);
    float*    regs   = (float*)carve((size_t)NPIX * 16);
    uint32_t* hist   = (uint32_t*)carve((size_t)HIST_SIZE * 4);
    uint32_t* ctl    = (uint32_t*)carve(256);
    uint64_t* cand   = (uint64_t*)carve((size_t)CAND_CAP * 8);
    float*    tops_s = (float*)carve((size_t)KSEL * 4);
    float*    boxes  = (float*)carve((size_t)KSEL * 16);
    uint64_t* mask   = (uint64_t*)carve((size_t)KSEL * 32 * 8);
    (void)ws_size; (void)in_sizes; (void)n_in; (void)out_size;

    hipMemsetAsync(hist, 0, (size_t)HIST_SIZE * 4, stream);
    hipMemsetAsync(ctl, 0, 256, stream);

    wexp2_k<<<512, 256, 0, stream>>>(w1, wexp2);
    conv_mfma<<<256, 512, 0, stream>>>(x, wexp2, b1, f);
    head_k<<<dim3(96, 4), 256, 0, stream>>>(f, wcls, wreg, part);
    combine_k<<<96, 256, 0, stream>>>(part, bcls, breg, scores, regs);
    hist_k<<<NPIX / 256, 256, 0, stream>>>(scores, hist);
    scan_k<<<1, 1024, 0, stream>>>(hist, ctl);
    collect_k<<<NPIX / 256, 256, 0, stream>>>(scores, ctl, cand);
    sort_decode_k<<<1, 1024, 0, stream>>>(cand, ctl, regs, hp, wp, tops_s, boxes);
    iou_k<<<dim3(KSEL / 64, KSEL / 64), 64, 0, stream>>>(boxes, mask);
    nms_k<<<1, 64, 0, stream>>>(tops_s, boxes, mask, out);
}